// Round 1
// baseline (9467.078 us; speedup 1.0000x reference)
//
#include <hip/hip_runtime.h>
#include <math.h>

#define NQ2 2048      // nx = nq = 2048
#define NT  4096      // nx + nq
#define NUU 16
#define FEPS 0.01f
#define NB  64
#define NBLK 32       // 2048 / 64

// ---------------- reductions ----------------
__device__ __forceinline__ float wave_reduce(float v) {
#pragma unroll
  for (int off = 32; off > 0; off >>= 1) v += __shfl_down(v, off, 64);
  return v;
}

__device__ __forceinline__ float block_reduce_256(float v) {
  __shared__ float sm[4];
  v = wave_reduce(v);
  if ((threadIdx.x & 63) == 0) sm[threadIdx.x >> 6] = v;
  __syncthreads();
  return (threadIdx.x == 0) ? (sm[0] + sm[1] + sm[2] + sm[3]) : 0.0f;
}

// ---------------- lam: inv(0.5*(||X2 row||^2 + eps)) ----------------
__global__ __launch_bounds__(256) void lam_kernel(const float* __restrict__ X,
                                                  float* __restrict__ invlam) {
  int row = blockIdx.x;
  const float* xr = X + (size_t)(NQ2 + row) * NT;
  float s = 0.f;
  for (int k = threadIdx.x * 4; k < NT; k += 1024) {
    float4 v = *(const float4*)(xr + k);
    s += v.x * v.x + v.y * v.y + v.z * v.z + v.w * v.w;
  }
  float tot = block_reduce_256(s);
  if (threadIdx.x == 0) invlam[row] = 1.0f / (0.5f * (tot + FEPS));
}

// ---------------- c = (U^T x)/lam + D12 u ----------------
__global__ __launch_bounds__(256) void c_kernel(const float* __restrict__ U,
                                                const float* __restrict__ D12,
                                                const float* __restrict__ x,
                                                const float* __restrict__ u,
                                                const float* __restrict__ invlam,
                                                float* __restrict__ c) {
  int q = blockIdx.x * 256 + threadIdx.x;
  float s = 0.f;
  for (int i = 0; i < NQ2; i += 4) {
    s += U[(size_t)(i + 0) * NQ2 + q] * x[i + 0];
    s += U[(size_t)(i + 1) * NQ2 + q] * x[i + 1];
    s += U[(size_t)(i + 2) * NQ2 + q] * x[i + 2];
    s += U[(size_t)(i + 3) * NQ2 + q] * x[i + 3];
  }
  float d = 0.f;
#pragma unroll
  for (int j = 0; j < NUU; j++) d += D12[(size_t)q * NUU + j] * u[j];
  c[q] = s * invlam[q] + d;
}

// ---------------- SYRK (lower tiles): C = A A^T (+ eps on diag) ----------------
__global__ __launch_bounds__(256) void syrk_lower_kernel(const float* __restrict__ A,
                                                         int lda, int K,
                                                         float* __restrict__ C, float eps) {
  int L = blockIdx.x;
  int bi = (int)((sqrtf(8.0f * (float)L + 1.0f) - 1.0f) * 0.5f);
  while ((bi + 1) * (bi + 2) / 2 <= L) bi++;
  while (bi * (bi + 1) / 2 > L) bi--;
  int bj = L - bi * (bi + 1) / 2;
  int row0 = bi * NB, col0 = bj * NB;

  __shared__ float As[16][68];
  __shared__ float Bs[16][68];
  int tid = threadIdx.x;
  int tx = tid & 15, ty = tid >> 4;
  int lr = tid >> 2;
  int lk = (tid & 3) << 2;
  float acc[4][4] = {{0.f}};
  for (int k0 = 0; k0 < K; k0 += 16) {
    float4 a = *(const float4*)(A + (size_t)(row0 + lr) * lda + k0 + lk);
    float4 b = *(const float4*)(A + (size_t)(col0 + lr) * lda + k0 + lk);
    As[lk + 0][lr] = a.x; As[lk + 1][lr] = a.y; As[lk + 2][lr] = a.z; As[lk + 3][lr] = a.w;
    Bs[lk + 0][lr] = b.x; Bs[lk + 1][lr] = b.y; Bs[lk + 2][lr] = b.z; Bs[lk + 3][lr] = b.w;
    __syncthreads();
#pragma unroll
    for (int k = 0; k < 16; k++) {
      float4 av = *(const float4*)&As[k][ty * 4];
      float4 bv = *(const float4*)&Bs[k][tx * 4];
      float aa[4] = {av.x, av.y, av.z, av.w};
      float bb[4] = {bv.x, bv.y, bv.z, bv.w};
#pragma unroll
      for (int i = 0; i < 4; i++)
#pragma unroll
        for (int j = 0; j < 4; j++) acc[i][j] = fmaf(aa[i], bb[j], acc[i][j]);
    }
    __syncthreads();
  }
#pragma unroll
  for (int i = 0; i < 4; i++) {
    int gi = row0 + ty * 4 + i;
    int gj0 = col0 + tx * 4;
    float4 o;
    o.x = acc[i][0]; o.y = acc[i][1]; o.z = acc[i][2]; o.w = acc[i][3];
    if (gi == gj0 + 0) o.x += eps;
    if (gi == gj0 + 1) o.y += eps;
    if (gi == gj0 + 2) o.z += eps;
    if (gi == gj0 + 3) o.w += eps;
    *(float4*)&C[(size_t)gi * NQ2 + gj0] = o;
  }
}

// ---------------- blocked forward substitution ----------------
// MODE 0: w_i = relu(c_i - (sum_{j<i} M[i,j] w_j) * invlam_i)    (M = H22, strict lower used)
// MODE 1: y_i = (r_i - sum_{j<i} L[i,j] y_j) / L[i,i]            (M = L)
template <int MODE>
__global__ __launch_bounds__(1024) void fwd_solve_kernel(const float* __restrict__ M_,
                                                         const float* __restrict__ rhs,
                                                         const float* __restrict__ invlam,
                                                         float* __restrict__ out) {
  __shared__ float partial[NQ2];
  __shared__ float il[NQ2];
  __shared__ float tile[NB][NB + 1];
  __shared__ float vblk[NB];
  int tid = threadIdx.x;
  for (int i = tid; i < NQ2; i += 1024) {
    partial[i] = rhs[i];
    if (MODE == 0) il[i] = invlam[i];
  }
  __syncthreads();
  for (int b = 0; b < NBLK; b++) {
    int b0 = b * NB;
    for (int e = tid; e < NB * NB; e += 1024) {
      int rr = e >> 6, cc = e & 63;
      tile[rr][cc] = M_[(size_t)(b0 + rr) * NQ2 + b0 + cc];
    }
    __syncthreads();
    if (tid < 64) {
      int lane = tid;
      float vreg = 0.f;
      float creg = partial[b0 + lane];
      float ilreg = (MODE == 0) ? il[b0 + lane] : 0.f;
      for (int i = 0; i < NB; i++) {
        float m = tile[i][lane];
        float p = (lane < i) ? m * vreg : 0.f;
        p += __shfl_xor(p, 1);  p += __shfl_xor(p, 2);  p += __shfl_xor(p, 4);
        p += __shfl_xor(p, 8);  p += __shfl_xor(p, 16); p += __shfl_xor(p, 32);
        if (lane == i) {
          if (MODE == 0) vreg = fmaxf(creg - p * ilreg, 0.f);
          else           vreg = (creg - p) / m;  // m = L[i,i] on lane i
        }
      }
      vblk[lane] = vreg;
      out[b0 + lane] = vreg;
    }
    __syncthreads();
    for (int i = b0 + NB + tid; i < NQ2; i += 1024) {
      const float* mr = M_ + (size_t)i * NQ2 + b0;
      float acc = 0.f;
#pragma unroll
      for (int j = 0; j < NB; j += 4) {
        float4 mv = *(const float4*)(mr + j);
        acc += mv.x * vblk[j] + mv.y * vblk[j + 1] + mv.z * vblk[j + 2] + mv.w * vblk[j + 3];
      }
      if (MODE == 0) partial[i] -= acc * il[i];
      else           partial[i] -= acc;
    }
    __syncthreads();
  }
}

// ---------------- blocked backward substitution: L^T z = y ----------------
__global__ __launch_bounds__(1024) void bwd_solve_kernel(const float* __restrict__ M_,
                                                         const float* __restrict__ rhs,
                                                         float* __restrict__ out) {
  __shared__ float partial[NQ2];
  __shared__ float tile[NB][NB + 1];  // tile[i][l] = L[b0+l][b0+i]
  __shared__ float vblk[NB];
  int tid = threadIdx.x;
  for (int i = tid; i < NQ2; i += 1024) partial[i] = rhs[i];
  __syncthreads();
  for (int b = NBLK - 1; b >= 0; b--) {
    int b0 = b * NB;
    for (int e = tid; e < NB * NB; e += 1024) {
      int rr = e >> 6, cc = e & 63;
      tile[cc][rr] = M_[(size_t)(b0 + rr) * NQ2 + b0 + cc];
    }
    __syncthreads();
    if (tid < 64) {
      int lane = tid;
      float vreg = 0.f;
      float creg = partial[b0 + lane];
      for (int i = NB - 1; i >= 0; i--) {
        float m = tile[i][lane];  // = L[b0+lane][b0+i]
        float p = (lane > i) ? m * vreg : 0.f;
        p += __shfl_xor(p, 1);  p += __shfl_xor(p, 2);  p += __shfl_xor(p, 4);
        p += __shfl_xor(p, 8);  p += __shfl_xor(p, 16); p += __shfl_xor(p, 32);
        if (lane == i) vreg = (creg - p) / m;  // m = L[i,i]
      }
      vblk[lane] = vreg;
      out[b0 + lane] = vreg;
    }
    __syncthreads();
    for (int i = tid; i < b0; i += 1024) {
      float acc = 0.f;
#pragma unroll 8
      for (int l = 0; l < NB; l++) acc += M_[(size_t)(b0 + l) * NQ2 + i] * vblk[l];
      partial[i] -= acc;
    }
    __syncthreads();
  }
}

// ---------------- Cholesky: diag factor ----------------
__global__ __launch_bounds__(64) void chol_diag_kernel(float* __restrict__ M_, int k) {
  __shared__ float A[NB][NB + 1];
  int tid = threadIdx.x;
  int b0 = k * NB;
  for (int cn = 0; cn < NB; cn++) A[tid][cn] = M_[(size_t)(b0 + tid) * NQ2 + b0 + cn];
  __syncthreads();
  for (int j = 0; j < NB; j++) {
    if (tid == j) A[j][j] = sqrtf(fmaxf(A[j][j], 1e-12f));
    __syncthreads();
    if (tid > j) A[tid][j] /= A[j][j];
    __syncthreads();
    if (tid > j) {
      float lij = A[tid][j];
      for (int jj = j + 1; jj <= tid; jj++) A[tid][jj] -= lij * A[jj][j];
    }
    __syncthreads();
  }
  for (int cn = 0; cn <= tid; cn++) M_[(size_t)(b0 + tid) * NQ2 + b0 + cn] = A[tid][cn];
}

// ---------------- Cholesky: panel solve L21 = A21 L11^{-T} ----------------
__global__ __launch_bounds__(256) void chol_panel_kernel(float* __restrict__ M_, int k) {
  __shared__ float L11[NB][NB + 1];
  int b0 = k * NB;
  for (int e = threadIdx.x; e < NB * NB; e += 256) {
    int rr = e >> 6, cc = e & 63;
    L11[rr][cc] = M_[(size_t)(b0 + rr) * NQ2 + b0 + cc];
  }
  __syncthreads();
  int row = b0 + NB + blockIdx.x * 256 + threadIdx.x;
  if (row >= NQ2) return;
  float v[NB];
  const float* ar = M_ + (size_t)row * NQ2 + b0;
#pragma unroll
  for (int j = 0; j < NB; j += 4) {
    float4 a = *(const float4*)(ar + j);
    v[j] = a.x; v[j + 1] = a.y; v[j + 2] = a.z; v[j + 3] = a.w;
  }
#pragma unroll
  for (int j = 0; j < NB; j++) {
    float s = v[j];
#pragma unroll
    for (int tt = 0; tt < j; tt++) s -= v[tt] * L11[j][tt];
    v[j] = s / L11[j][j];
  }
  float* wr = M_ + (size_t)row * NQ2 + b0;
#pragma unroll
  for (int j = 0; j < NB; j += 4) {
    float4 a; a.x = v[j]; a.y = v[j + 1]; a.z = v[j + 2]; a.w = v[j + 3];
    *(float4*)(wr + j) = a;
  }
}

// ---------------- Cholesky: trailing update A22 -= L21 L21^T (lower tiles) --------
__global__ __launch_bounds__(256) void chol_trail_kernel(float* __restrict__ M_, int k) {
  int L = blockIdx.x;
  int bi_ = (int)((sqrtf(8.0f * (float)L + 1.0f) - 1.0f) * 0.5f);
  while ((bi_ + 1) * (bi_ + 2) / 2 <= L) bi_++;
  while (bi_ * (bi_ + 1) / 2 > L) bi_--;
  int bj_ = L - bi_ * (bi_ + 1) / 2;
  int bi = k + 1 + bi_, bj = k + 1 + bj_;
  int row0 = bi * NB, col0 = bj * NB, kc = k * NB;
  __shared__ float As[NB][NB + 1];
  __shared__ float Bs[NB][NB + 1];
  int tid = threadIdx.x;
  for (int e = tid; e < NB * NB; e += 256) {
    int rr = e >> 6, cc = e & 63;
    As[rr][cc] = M_[(size_t)(row0 + rr) * NQ2 + kc + cc];
    Bs[rr][cc] = M_[(size_t)(col0 + rr) * NQ2 + kc + cc];
  }
  __syncthreads();
  int tx = tid & 15, ty = tid >> 4;
  float acc[4][4] = {{0.f}};
#pragma unroll 8
  for (int t = 0; t < NB; t++) {
    float aa[4], bb[4];
#pragma unroll
    for (int i = 0; i < 4; i++) aa[i] = As[ty * 4 + i][t];
#pragma unroll
    for (int j = 0; j < 4; j++) bb[j] = Bs[tx * 4 + j][t];
#pragma unroll
    for (int i = 0; i < 4; i++)
#pragma unroll
      for (int j = 0; j < 4; j++) acc[i][j] = fmaf(aa[i], bb[j], acc[i][j]);
  }
#pragma unroll
  for (int i = 0; i < 4; i++) {
    float* cp = &M_[(size_t)(row0 + ty * 4 + i) * NQ2 + col0 + tx * 4];
    float4 v = *(const float4*)cp;
    v.x -= acc[i][0]; v.y -= acc[i][1]; v.z -= acc[i][2]; v.w -= acc[i][3];
    *(float4*)cp = v;
  }
}

// ---------------- t = -0.5 X1^T x - X2^T w (split over row chunks) ----------------
#define TCH 32
__global__ __launch_bounds__(256) void t_partial_kernel(const float* __restrict__ X,
                                                        const float* __restrict__ x,
                                                        const float* __restrict__ w,
                                                        float* __restrict__ tpart) {
  int k4 = (blockIdx.x * 256 + threadIdx.x) * 4;
  int chunk = blockIdx.y;
  int i0 = chunk * (NT / TCH);
  float4 acc = {0.f, 0.f, 0.f, 0.f};
  for (int i = i0; i < i0 + NT / TCH; i++) {
    float cf = (i < NQ2) ? (-0.5f * x[i]) : (-w[i - NQ2]);
    float4 xv = *(const float4*)(X + (size_t)i * NT + k4);
    acc.x += cf * xv.x; acc.y += cf * xv.y; acc.z += cf * xv.z; acc.w += cf * xv.w;
  }
  *(float4*)(tpart + (size_t)chunk * NT + k4) = acc;
}

__global__ __launch_bounds__(256) void t_reduce_kernel(const float* __restrict__ tpart,
                                                       float* __restrict__ t) {
  int k = blockIdx.x * 256 + threadIdx.x;
  float s = 0.f;
#pragma unroll 8
  for (int ch = 0; ch < TCH; ch++) s += tpart[(size_t)ch * NT + k];
  t[k] = s;
}

// -------- r = X1 t - 0.5 Y1 x - U w - 0.5 eps x  (per-row dot reductions) --------
__global__ __launch_bounds__(256) void r_kernel(const float* __restrict__ X,
                                                const float* __restrict__ Y1,
                                                const float* __restrict__ U,
                                                const float* __restrict__ t,
                                                const float* __restrict__ x,
                                                const float* __restrict__ w,
                                                float* __restrict__ r) {
  int row = blockIdx.x;
  float s1 = 0.f, s2 = 0.f, s3 = 0.f;
  const float* xr = X + (size_t)row * NT;
  for (int k = threadIdx.x * 4; k < NT; k += 1024) {
    float4 a = *(const float4*)(xr + k);
    float4 b = *(const float4*)(t + k);
    s1 += a.x * b.x + a.y * b.y + a.z * b.z + a.w * b.w;
  }
  const float* yr = Y1 + (size_t)row * NQ2;
  const float* ur = U + (size_t)row * NQ2;
  for (int k = threadIdx.x * 4; k < NQ2; k += 1024) {
    float4 a = *(const float4*)(yr + k);
    float4 b = *(const float4*)(x + k);
    s2 += a.x * b.x + a.y * b.y + a.z * b.z + a.w * b.w;
    float4 c2 = *(const float4*)(ur + k);
    float4 d2 = *(const float4*)(w + k);
    s3 += c2.x * d2.x + c2.y * d2.y + c2.z * d2.z + c2.w * d2.w;
  }
  float v = s1 - 0.5f * s2 - s3;
  float tot = block_reduce_256(v);
  if (threadIdx.x == 0) r[row] = tot - 0.5f * FEPS * x[row];
}

// ---------------- r += 0.5 * Y1^T x ----------------
__global__ __launch_bounds__(256) void r2_kernel(const float* __restrict__ Y1,
                                                 const float* __restrict__ x,
                                                 float* __restrict__ r) {
  int i = blockIdx.x * 256 + threadIdx.x;
  float s = 0.f;
#pragma unroll 4
  for (int j = 0; j < NQ2; j++) s += Y1[(size_t)j * NQ2 + i] * x[j];
  r[i] += 0.5f * s;
}

// ---------------- IR: pz1 = XP^T z ----------------
__global__ __launch_bounds__(256) void pz1_kernel(const float* __restrict__ XP,
                                                  const float* __restrict__ z,
                                                  float* __restrict__ pz1) {
  int kcol = blockIdx.x * 256 + threadIdx.x;
  float s = 0.f;
#pragma unroll 4
  for (int i = 0; i < NQ2; i++) s += XP[(size_t)i * NQ2 + kcol] * z[i];
  pz1[kcol] = s;
}

// ---------------- IR: res = r - (XP pz1 + eps z) ----------------
__global__ __launch_bounds__(256) void pz2_res_kernel(const float* __restrict__ XP,
                                                      const float* __restrict__ pz1,
                                                      const float* __restrict__ z,
                                                      const float* __restrict__ r,
                                                      float* __restrict__ res) {
  int row = blockIdx.x;
  float s = 0.f;
  const float* xr = XP + (size_t)row * NQ2;
  for (int k = threadIdx.x * 4; k < NQ2; k += 1024) {
    float4 a = *(const float4*)(xr + k);
    float4 b = *(const float4*)(pz1 + k);
    s += a.x * b.x + a.y * b.y + a.z * b.z + a.w * b.w;
  }
  float tot = block_reduce_256(s);
  if (threadIdx.x == 0) res[row] = r[row] - (tot + FEPS * z[row]);
}

__global__ __launch_bounds__(256) void axpy_kernel(float* __restrict__ z,
                                                   const float* __restrict__ dz) {
  int i = blockIdx.x * 256 + threadIdx.x;
  z[i] += dz[i];
}

// ---------------- out = z + B2 u ----------------
__global__ __launch_bounds__(256) void out_kernel(const float* __restrict__ z,
                                                  const float* __restrict__ B2,
                                                  const float* __restrict__ u,
                                                  float* __restrict__ out) {
  int i = blockIdx.x * 256 + threadIdx.x;
  float s = 0.f;
#pragma unroll
  for (int j = 0; j < NUU; j++) s += B2[(size_t)i * NUU + j] * u[j];
  out[i] = z[i] + s;
}

extern "C" void kernel_launch(void* const* d_in, const int* in_sizes, int n_in,
                              void* d_out, int out_size, void* d_ws, size_t ws_size,
                              hipStream_t stream) {
  (void)in_sizes; (void)n_in; (void)out_size; (void)ws_size;
  const float* x   = (const float*)d_in[1];
  const float* u   = (const float*)d_in[2];
  const float* X   = (const float*)d_in[3];
  const float* U   = (const float*)d_in[4];
  const float* Y1  = (const float*)d_in[5];
  const float* XP  = (const float*)d_in[6];
  const float* B2  = (const float*)d_in[7];
  const float* D12 = (const float*)d_in[8];
  float* out = (float*)d_out;

  float* ws     = (float*)d_ws;
  float* M      = ws;                           // 2048*2048, holds H22 then P/L
  float* vecs   = ws + (size_t)NQ2 * NQ2;
  float* invlam = vecs;
  float* c      = vecs + 2048;
  float* w      = vecs + 4096;
  float* r      = vecs + 6144;
  float* y      = vecs + 8192;
  float* z      = vecs + 10240;
  float* dz     = vecs + 12288;
  float* res    = vecs + 14336;
  float* t      = vecs + 16384;                 // 4096 (also reused as pz1)
  float* tpart  = vecs + 20480;                 // 32*4096

  // lam, c
  lam_kernel<<<NQ2, 256, 0, stream>>>(X, invlam);
  c_kernel<<<NQ2 / 256, 256, 0, stream>>>(U, D12, x, u, invlam, c);

  // H22 (strict lower used) into M, then sequential relu-triangular solve for w
  syrk_lower_kernel<<<NBLK * (NBLK + 1) / 2, 256, 0, stream>>>(X + (size_t)NQ2 * NT, NT, NT, M, 0.0f);
  fwd_solve_kernel<0><<<1, 1024, 0, stream>>>(M, c, invlam, w);

  // r = -0.5 X1 X1^T x - X1 X2^T w - 0.5 Y1 x + 0.5 Y1^T x - U w - 0.5 eps x
  dim3 tg(4, TCH);
  t_partial_kernel<<<tg, 256, 0, stream>>>(X, x, w, tpart);
  t_reduce_kernel<<<NT / 256, 256, 0, stream>>>(tpart, t);
  r_kernel<<<NQ2, 256, 0, stream>>>(X, Y1, U, t, x, w, r);
  r2_kernel<<<NQ2 / 256, 256, 0, stream>>>(Y1, x, r);

  // P = XP XP^T + eps I (lower) into M, Cholesky in place
  syrk_lower_kernel<<<NBLK * (NBLK + 1) / 2, 256, 0, stream>>>(XP, NQ2, NQ2, M, FEPS);
  for (int k = 0; k < NBLK; k++) {
    chol_diag_kernel<<<1, 64, 0, stream>>>(M, k);
    int rows_below = NQ2 - (k + 1) * NB;
    if (rows_below > 0) {
      chol_panel_kernel<<<(rows_below + 255) / 256, 256, 0, stream>>>(M, k);
      int m = NBLK - 1 - k;
      chol_trail_kernel<<<m * (m + 1) / 2, 256, 0, stream>>>(M, k);
    }
  }

  // solve P z = r
  fwd_solve_kernel<1><<<1, 1024, 0, stream>>>(M, r, invlam, y);
  bwd_solve_kernel<<<1, 1024, 0, stream>>>(M, y, z);

  // 2 steps of iterative refinement (residual via matvecs, P never re-formed)
  for (int it = 0; it < 2; it++) {
    pz1_kernel<<<NQ2 / 256, 256, 0, stream>>>(XP, z, t);
    pz2_res_kernel<<<NQ2, 256, 0, stream>>>(XP, t, z, r, res);
    fwd_solve_kernel<1><<<1, 1024, 0, stream>>>(M, res, invlam, y);
    bwd_solve_kernel<<<1, 1024, 0, stream>>>(M, y, dz);
    axpy_kernel<<<NQ2 / 256, 256, 0, stream>>>(z, dz);
  }

  out_kernel<<<NQ2 / 256, 256, 0, stream>>>(z, B2, u, out);
}

// Round 2
// 8997.202 us; speedup vs baseline: 1.0522x; 1.0522x over previous
//
#include <hip/hip_runtime.h>
#include <math.h>

#define NQ2 2048      // nx = nq = 2048
#define NT  4096      // nx + nq
#define NUU 16
#define FEPS 0.01f
#define NB  64
#define NBLK 32       // 2048 / 64
#define ST  128       // syrk tile
#define SBK 16
#define GCH 16        // split-K chunks for transposed GEMVs

// ---------------- reductions ----------------
__device__ __forceinline__ float wave_reduce(float v) {
#pragma unroll
  for (int off = 32; off > 0; off >>= 1) v += __shfl_down(v, off, 64);
  return v;
}

__device__ __forceinline__ float block_reduce_256(float v) {
  __shared__ float sm[4];
  v = wave_reduce(v);
  if ((threadIdx.x & 63) == 0) sm[threadIdx.x >> 6] = v;
  __syncthreads();
  return (threadIdx.x == 0) ? (sm[0] + sm[1] + sm[2] + sm[3]) : 0.0f;
}

// ---------------- lam: inv(0.5*(||X2 row||^2 + eps)) ----------------
__global__ __launch_bounds__(256) void lam_kernel(const float* __restrict__ X,
                                                  float* __restrict__ invlam) {
  int row = blockIdx.x;
  const float* xr = X + (size_t)(NQ2 + row) * NT;
  float s = 0.f;
  for (int k = threadIdx.x * 4; k < NT; k += 1024) {
    float4 v = *(const float4*)(xr + k);
    s += v.x * v.x + v.y * v.y + v.z * v.z + v.w * v.w;
  }
  float tot = block_reduce_256(s);
  if (threadIdx.x == 0) invlam[row] = 1.0f / (0.5f * (tot + FEPS));
}

// ---------------- split-K transposed GEMV: part[ch][col] = sum_i A[i][col] v[i] ----
__global__ __launch_bounds__(256) void tgemv_part_kernel(const float* __restrict__ A,
                                                         const float* __restrict__ v,
                                                         float* __restrict__ part) {
  int col = blockIdx.x * 256 + threadIdx.x;
  int ch = blockIdx.y;
  int i0 = ch * (NQ2 / GCH), i1 = i0 + NQ2 / GCH;
  float s = 0.f;
#pragma unroll 4
  for (int i = i0; i < i1; i++) s = fmaf(A[(size_t)i * NQ2 + col], v[i], s);
  part[(size_t)ch * NQ2 + col] = s;
}

// FM 0: c = sum*invlam + D12 u   FM 1: r += 0.5*sum   FM 2: dst = sum
template <int FM>
__global__ __launch_bounds__(256) void finish_kernel(const float* __restrict__ part,
                                                     const float* __restrict__ invlam,
                                                     const float* __restrict__ D12,
                                                     const float* __restrict__ u,
                                                     float* __restrict__ dst) {
  int col = blockIdx.x * 256 + threadIdx.x;
  float s = 0.f;
#pragma unroll
  for (int ch = 0; ch < GCH; ch++) s += part[(size_t)ch * NQ2 + col];
  if (FM == 0) {
    float d = 0.f;
#pragma unroll
    for (int j = 0; j < NUU; j++) d += D12[(size_t)col * NUU + j] * u[j];
    dst[col] = s * invlam[col] + d;
  } else if (FM == 1) {
    dst[col] += 0.5f * s;
  } else {
    dst[col] = s;
  }
}

// ---------------- SYRK (lower 128-tiles): C = A A^T (+ eps on diag) ----------------
__global__ __launch_bounds__(256) void syrk_lower_kernel(const float* __restrict__ A,
                                                         int lda, int K,
                                                         float* __restrict__ C, float eps) {
  int L = blockIdx.x;
  int bi = (int)((sqrtf(8.0f * (float)L + 1.0f) - 1.0f) * 0.5f);
  while ((bi + 1) * (bi + 2) / 2 <= L) bi++;
  while (bi * (bi + 1) / 2 > L) bi--;
  int bj = L - bi * (bi + 1) / 2;
  int row0 = bi * ST, col0 = bj * ST;

  __shared__ float As[SBK][ST];
  __shared__ float Bs[SBK][ST];
  int tid = threadIdx.x;
  int tx = tid & 15, ty = tid >> 4;
  int sr = tid >> 1;            // staging row 0..127
  int ks = (tid & 1) * 8;       // staging k offset 0 or 8

  float4 a0, a1, b0, b1;
  {
    const float* ap = A + (size_t)(row0 + sr) * lda + ks;
    const float* bp = A + (size_t)(col0 + sr) * lda + ks;
    a0 = *(const float4*)(ap); a1 = *(const float4*)(ap + 4);
    b0 = *(const float4*)(bp); b1 = *(const float4*)(bp + 4);
  }

  float acc[8][8] = {{0.f}};
  for (int k0 = 0; k0 < K; k0 += SBK) {
    __syncthreads();
    As[ks + 0][sr] = a0.x; As[ks + 1][sr] = a0.y; As[ks + 2][sr] = a0.z; As[ks + 3][sr] = a0.w;
    As[ks + 4][sr] = a1.x; As[ks + 5][sr] = a1.y; As[ks + 6][sr] = a1.z; As[ks + 7][sr] = a1.w;
    Bs[ks + 0][sr] = b0.x; Bs[ks + 1][sr] = b0.y; Bs[ks + 2][sr] = b0.z; Bs[ks + 3][sr] = b0.w;
    Bs[ks + 4][sr] = b1.x; Bs[ks + 5][sr] = b1.y; Bs[ks + 6][sr] = b1.z; Bs[ks + 7][sr] = b1.w;
    __syncthreads();
    if (k0 + SBK < K) {
      const float* ap = A + (size_t)(row0 + sr) * lda + k0 + SBK + ks;
      const float* bp = A + (size_t)(col0 + sr) * lda + k0 + SBK + ks;
      a0 = *(const float4*)(ap); a1 = *(const float4*)(ap + 4);
      b0 = *(const float4*)(bp); b1 = *(const float4*)(bp + 4);
    }
#pragma unroll
    for (int k = 0; k < SBK; k++) {
      float4 aL = *(const float4*)&As[k][ty * 4];
      float4 aH = *(const float4*)&As[k][64 + ty * 4];
      float4 bL = *(const float4*)&Bs[k][tx * 4];
      float4 bH = *(const float4*)&Bs[k][64 + tx * 4];
      float aa[8] = {aL.x, aL.y, aL.z, aL.w, aH.x, aH.y, aH.z, aH.w};
      float bb[8] = {bL.x, bL.y, bL.z, bL.w, bH.x, bH.y, bH.z, bH.w};
#pragma unroll
      for (int i = 0; i < 8; i++)
#pragma unroll
        for (int j = 0; j < 8; j++) acc[i][j] = fmaf(aa[i], bb[j], acc[i][j]);
    }
  }

  bool diag = (row0 == col0);
#pragma unroll
  for (int ii = 0; ii < 8; ii++) {
    int gi = row0 + ((ii >> 2) * 64) + ty * 4 + (ii & 3);
#pragma unroll
    for (int half = 0; half < 2; half++) {
      int gj0 = col0 + half * 64 + tx * 4;
      float4 o;
      o.x = acc[ii][half * 4 + 0]; o.y = acc[ii][half * 4 + 1];
      o.z = acc[ii][half * 4 + 2]; o.w = acc[ii][half * 4 + 3];
      if (diag) {
        if (gi == gj0 + 0) o.x += eps;
        if (gi == gj0 + 1) o.y += eps;
        if (gi == gj0 + 2) o.z += eps;
        if (gi == gj0 + 3) o.w += eps;
      }
      *(float4*)&C[(size_t)gi * NQ2 + gj0] = o;
    }
  }
}

// ---------------- blocked forward substitution (coalesced GEMV) ----------------
// MODE 0: w_i = relu(c_i - (sum_{j<i} M[i,j] w_j) * invlam_i)    (M = H22, strict lower)
// MODE 1: y_i = (r_i - sum_{j<i} L[i,j] y_j) / L[i,i]            (M = L)
template <int MODE>
__global__ __launch_bounds__(1024) void fwd_solve_kernel(const float* __restrict__ M_,
                                                         const float* __restrict__ rhs,
                                                         const float* __restrict__ invlam,
                                                         float* __restrict__ out) {
  __shared__ float partial[NQ2];
  __shared__ float il[NQ2];
  __shared__ float tile[NB][NB + 1];
  __shared__ float vblk[NB];
  int tid = threadIdx.x;
  int rgrp = tid >> 4;    // 0..63
  int l16 = tid & 15;     // 0..15
  for (int i = tid; i < NQ2; i += 1024) {
    partial[i] = rhs[i];
    if (MODE == 0) il[i] = invlam[i];
  }
  __syncthreads();
  for (int b = 0; b < NBLK; b++) {
    int b0 = b * NB;
    for (int e = tid; e < NB * NB; e += 1024) {
      int rr = e >> 6, cc = e & 63;
      tile[rr][cc] = M_[(size_t)(b0 + rr) * NQ2 + b0 + cc];
    }
    __syncthreads();
    if (tid < 64) {
      int lane = tid;
      float vreg = 0.f;
      float creg = partial[b0 + lane];
      float ilreg = (MODE == 0) ? il[b0 + lane] : 0.f;
      for (int i = 0; i < NB; i++) {
        float m = tile[i][lane];
        float p = (lane < i) ? m * vreg : 0.f;
        p += __shfl_xor(p, 1);  p += __shfl_xor(p, 2);  p += __shfl_xor(p, 4);
        p += __shfl_xor(p, 8);  p += __shfl_xor(p, 16); p += __shfl_xor(p, 32);
        if (lane == i) {
          if (MODE == 0) vreg = fmaxf(creg - p * ilreg, 0.f);
          else           vreg = (creg - p) / m;
        }
      }
      vblk[lane] = vreg;
      out[b0 + lane] = vreg;
    }
    __syncthreads();
    // coalesced cross-block GEMV: 16 lanes per row
    float4 vb = *(const float4*)&vblk[l16 * 4];
    for (int base = b0 + NB; base < NQ2; base += 64) {
      int row = base + rgrp;
      float acc = 0.f;
      if (row < NQ2) {
        float4 mv = *(const float4*)(M_ + (size_t)row * NQ2 + b0 + l16 * 4);
        acc = mv.x * vb.x + mv.y * vb.y + mv.z * vb.z + mv.w * vb.w;
      }
      acc += __shfl_xor(acc, 1); acc += __shfl_xor(acc, 2);
      acc += __shfl_xor(acc, 4); acc += __shfl_xor(acc, 8);
      if (l16 == 0 && row < NQ2) {
        if (MODE == 0) partial[row] -= acc * il[row];
        else           partial[row] -= acc;
      }
    }
    __syncthreads();
  }
}

// ---------------- blocked backward substitution: L^T z = y ----------------
__global__ __launch_bounds__(1024) void bwd_solve_kernel(const float* __restrict__ M_,
                                                         const float* __restrict__ rhs,
                                                         float* __restrict__ out) {
  __shared__ float partial[NQ2];
  __shared__ float tile[NB][NB + 1];  // tile[i][l] = L[b0+l][b0+i]
  __shared__ float vblk[NB];
  int tid = threadIdx.x;
  for (int i = tid; i < NQ2; i += 1024) partial[i] = rhs[i];
  __syncthreads();
  for (int b = NBLK - 1; b >= 0; b--) {
    int b0 = b * NB;
    for (int e = tid; e < NB * NB; e += 1024) {
      int rr = e >> 6, cc = e & 63;
      tile[cc][rr] = M_[(size_t)(b0 + rr) * NQ2 + b0 + cc];
    }
    __syncthreads();
    if (tid < 64) {
      int lane = tid;
      float vreg = 0.f;
      float creg = partial[b0 + lane];
      for (int i = NB - 1; i >= 0; i--) {
        float m = tile[i][lane];  // = L[b0+lane][b0+i]
        float p = (lane > i) ? m * vreg : 0.f;
        p += __shfl_xor(p, 1);  p += __shfl_xor(p, 2);  p += __shfl_xor(p, 4);
        p += __shfl_xor(p, 8);  p += __shfl_xor(p, 16); p += __shfl_xor(p, 32);
        if (lane == i) vreg = (creg - p) / m;
      }
      vblk[lane] = vreg;
      out[b0 + lane] = vreg;
    }
    __syncthreads();
    for (int i = tid; i < b0; i += 1024) {
      float acc = 0.f;
#pragma unroll 8
      for (int l = 0; l < NB; l++) acc += M_[(size_t)(b0 + l) * NQ2 + i] * vblk[l];
      partial[i] -= acc;
    }
    __syncthreads();
  }
}

// ---------------- Cholesky: diag factor ----------------
__global__ __launch_bounds__(64) void chol_diag_kernel(float* __restrict__ M_, int k) {
  __shared__ float A[NB][NB + 1];
  int tid = threadIdx.x;
  int b0 = k * NB;
  for (int cn = 0; cn < NB; cn++) A[tid][cn] = M_[(size_t)(b0 + tid) * NQ2 + b0 + cn];
  __syncthreads();
  for (int j = 0; j < NB; j++) {
    if (tid == j) A[j][j] = sqrtf(fmaxf(A[j][j], 1e-12f));
    __syncthreads();
    if (tid > j) A[tid][j] /= A[j][j];
    __syncthreads();
    if (tid > j) {
      float lij = A[tid][j];
      for (int jj = j + 1; jj <= tid; jj++) A[tid][jj] -= lij * A[jj][j];
    }
    __syncthreads();
  }
  for (int cn = 0; cn <= tid; cn++) M_[(size_t)(b0 + tid) * NQ2 + b0 + cn] = A[tid][cn];
}

// ---------------- Cholesky: panel solve L21 = A21 L11^{-T} ----------------
__global__ __launch_bounds__(256) void chol_panel_kernel(float* __restrict__ M_, int k) {
  __shared__ float L11[NB][NB + 1];
  int b0 = k * NB;
  for (int e = threadIdx.x; e < NB * NB; e += 256) {
    int rr = e >> 6, cc = e & 63;
    L11[rr][cc] = M_[(size_t)(b0 + rr) * NQ2 + b0 + cc];
  }
  __syncthreads();
  int row = b0 + NB + blockIdx.x * 256 + threadIdx.x;
  if (row >= NQ2) return;
  float v[NB];
  const float* ar = M_ + (size_t)row * NQ2 + b0;
#pragma unroll
  for (int j = 0; j < NB; j += 4) {
    float4 a = *(const float4*)(ar + j);
    v[j] = a.x; v[j + 1] = a.y; v[j + 2] = a.z; v[j + 3] = a.w;
  }
#pragma unroll
  for (int j = 0; j < NB; j++) {
    float s = v[j];
#pragma unroll
    for (int tt = 0; tt < j; tt++) s -= v[tt] * L11[j][tt];
    v[j] = s / L11[j][j];
  }
  float* wr = M_ + (size_t)row * NQ2 + b0;
#pragma unroll
  for (int j = 0; j < NB; j += 4) {
    float4 a; a.x = v[j]; a.y = v[j + 1]; a.z = v[j + 2]; a.w = v[j + 3];
    *(float4*)(wr + j) = a;
  }
}

// ---------------- Cholesky: trailing update A22 -= L21 L21^T (lower tiles) --------
__global__ __launch_bounds__(256) void chol_trail_kernel(float* __restrict__ M_, int k) {
  int L = blockIdx.x;
  int bi_ = (int)((sqrtf(8.0f * (float)L + 1.0f) - 1.0f) * 0.5f);
  while ((bi_ + 1) * (bi_ + 2) / 2 <= L) bi_++;
  while (bi_ * (bi_ + 1) / 2 > L) bi_--;
  int bj_ = L - bi_ * (bi_ + 1) / 2;
  int bi = k + 1 + bi_, bj = k + 1 + bj_;
  int row0 = bi * NB, col0 = bj * NB, kc = k * NB;
  __shared__ float As[NB][NB + 1];
  __shared__ float Bs[NB][NB + 1];
  int tid = threadIdx.x;
  for (int e = tid; e < NB * NB; e += 256) {
    int rr = e >> 6, cc = e & 63;
    As[rr][cc] = M_[(size_t)(row0 + rr) * NQ2 + kc + cc];
    Bs[rr][cc] = M_[(size_t)(col0 + rr) * NQ2 + kc + cc];
  }
  __syncthreads();
  int tx = tid & 15, ty = tid >> 4;
  float acc[4][4] = {{0.f}};
#pragma unroll 8
  for (int t = 0; t < NB; t++) {
    float aa[4], bb[4];
#pragma unroll
    for (int i = 0; i < 4; i++) aa[i] = As[ty * 4 + i][t];
#pragma unroll
    for (int j = 0; j < 4; j++) bb[j] = Bs[tx * 4 + j][t];
#pragma unroll
    for (int i = 0; i < 4; i++)
#pragma unroll
      for (int j = 0; j < 4; j++) acc[i][j] = fmaf(aa[i], bb[j], acc[i][j]);
  }
#pragma unroll
  for (int i = 0; i < 4; i++) {
    float* cp = &M_[(size_t)(row0 + ty * 4 + i) * NQ2 + col0 + tx * 4];
    float4 v = *(const float4*)cp;
    v.x -= acc[i][0]; v.y -= acc[i][1]; v.z -= acc[i][2]; v.w -= acc[i][3];
    *(float4*)cp = v;
  }
}

// ---------------- t = -0.5 X1^T x - X2^T w (split over row chunks) ----------------
#define TCH 32
__global__ __launch_bounds__(256) void t_partial_kernel(const float* __restrict__ X,
                                                        const float* __restrict__ x,
                                                        const float* __restrict__ w,
                                                        float* __restrict__ tpart) {
  int k4 = (blockIdx.x * 256 + threadIdx.x) * 4;
  int chunk = blockIdx.y;
  int i0 = chunk * (NT / TCH);
  float4 acc = {0.f, 0.f, 0.f, 0.f};
  for (int i = i0; i < i0 + NT / TCH; i++) {
    float cf = (i < NQ2) ? (-0.5f * x[i]) : (-w[i - NQ2]);
    float4 xv = *(const float4*)(X + (size_t)i * NT + k4);
    acc.x += cf * xv.x; acc.y += cf * xv.y; acc.z += cf * xv.z; acc.w += cf * xv.w;
  }
  *(float4*)(tpart + (size_t)chunk * NT + k4) = acc;
}

__global__ __launch_bounds__(256) void t_reduce_kernel(const float* __restrict__ tpart,
                                                       float* __restrict__ t) {
  int k = blockIdx.x * 256 + threadIdx.x;
  float s = 0.f;
#pragma unroll 8
  for (int ch = 0; ch < TCH; ch++) s += tpart[(size_t)ch * NT + k];
  t[k] = s;
}

// -------- r = X1 t - 0.5 Y1 x - U w - 0.5 eps x  (per-row dot reductions) --------
__global__ __launch_bounds__(256) void r_kernel(const float* __restrict__ X,
                                                const float* __restrict__ Y1,
                                                const float* __restrict__ U,
                                                const float* __restrict__ t,
                                                const float* __restrict__ x,
                                                const float* __restrict__ w,
                                                float* __restrict__ r) {
  int row = blockIdx.x;
  float s1 = 0.f, s2 = 0.f, s3 = 0.f;
  const float* xr = X + (size_t)row * NT;
  for (int k = threadIdx.x * 4; k < NT; k += 1024) {
    float4 a = *(const float4*)(xr + k);
    float4 b = *(const float4*)(t + k);
    s1 += a.x * b.x + a.y * b.y + a.z * b.z + a.w * b.w;
  }
  const float* yr = Y1 + (size_t)row * NQ2;
  const float* ur = U + (size_t)row * NQ2;
  for (int k = threadIdx.x * 4; k < NQ2; k += 1024) {
    float4 a = *(const float4*)(yr + k);
    float4 b = *(const float4*)(x + k);
    s2 += a.x * b.x + a.y * b.y + a.z * b.z + a.w * b.w;
    float4 c2 = *(const float4*)(ur + k);
    float4 d2 = *(const float4*)(w + k);
    s3 += c2.x * d2.x + c2.y * d2.y + c2.z * d2.z + c2.w * d2.w;
  }
  float v = s1 - 0.5f * s2 - s3;
  float tot = block_reduce_256(v);
  if (threadIdx.x == 0) r[row] = tot - 0.5f * FEPS * x[row];
}

// ---------------- IR: res = r - (XP pz1 + eps z) ----------------
__global__ __launch_bounds__(256) void pz2_res_kernel(const float* __restrict__ XP,
                                                      const float* __restrict__ pz1,
                                                      const float* __restrict__ z,
                                                      const float* __restrict__ r,
                                                      float* __restrict__ res) {
  int row = blockIdx.x;
  float s = 0.f;
  const float* xr = XP + (size_t)row * NQ2;
  for (int k = threadIdx.x * 4; k < NQ2; k += 1024) {
    float4 a = *(const float4*)(xr + k);
    float4 b = *(const float4*)(pz1 + k);
    s += a.x * b.x + a.y * b.y + a.z * b.z + a.w * b.w;
  }
  float tot = block_reduce_256(s);
  if (threadIdx.x == 0) res[row] = r[row] - (tot + FEPS * z[row]);
}

__global__ __launch_bounds__(256) void axpy_kernel(float* __restrict__ z,
                                                   const float* __restrict__ dz) {
  int i = blockIdx.x * 256 + threadIdx.x;
  z[i] += dz[i];
}

// ---------------- out = z + B2 u ----------------
__global__ __launch_bounds__(256) void out_kernel(const float* __restrict__ z,
                                                  const float* __restrict__ B2,
                                                  const float* __restrict__ u,
                                                  float* __restrict__ out) {
  int i = blockIdx.x * 256 + threadIdx.x;
  float s = 0.f;
#pragma unroll
  for (int j = 0; j < NUU; j++) s += B2[(size_t)i * NUU + j] * u[j];
  out[i] = z[i] + s;
}

extern "C" void kernel_launch(void* const* d_in, const int* in_sizes, int n_in,
                              void* d_out, int out_size, void* d_ws, size_t ws_size,
                              hipStream_t stream) {
  (void)in_sizes; (void)n_in; (void)out_size; (void)ws_size;
  const float* x   = (const float*)d_in[1];
  const float* u   = (const float*)d_in[2];
  const float* X   = (const float*)d_in[3];
  const float* U   = (const float*)d_in[4];
  const float* Y1  = (const float*)d_in[5];
  const float* XP  = (const float*)d_in[6];
  const float* B2  = (const float*)d_in[7];
  const float* D12 = (const float*)d_in[8];
  float* out = (float*)d_out;

  float* ws     = (float*)d_ws;
  float* M      = ws;                           // 2048*2048, holds H22 then P/L
  float* vecs   = ws + (size_t)NQ2 * NQ2;
  float* invlam = vecs;
  float* c      = vecs + 2048;
  float* w      = vecs + 4096;
  float* r      = vecs + 6144;
  float* y      = vecs + 8192;
  float* z      = vecs + 10240;
  float* dz     = vecs + 12288;
  float* res    = vecs + 14336;
  float* t      = vecs + 16384;                 // 4096 (also reused as pz1)
  float* tpart  = vecs + 20480;                 // 32*4096 (also reused as gpart 16*2048)
  float* gpart  = tpart;

  int nsyrk = (NQ2 / ST) * (NQ2 / ST + 1) / 2;  // 136
  dim3 gdim(NQ2 / 256, GCH);

  // lam, c = (U^T x)/lam + D12 u
  lam_kernel<<<NQ2, 256, 0, stream>>>(X, invlam);
  tgemv_part_kernel<<<gdim, 256, 0, stream>>>(U, x, gpart);
  finish_kernel<0><<<NQ2 / 256, 256, 0, stream>>>(gpart, invlam, D12, u, c);

  // H22 (strict lower used) into M, then sequential relu-triangular solve for w
  syrk_lower_kernel<<<nsyrk, 256, 0, stream>>>(X + (size_t)NQ2 * NT, NT, NT, M, 0.0f);
  fwd_solve_kernel<0><<<1, 1024, 0, stream>>>(M, c, invlam, w);

  // r = -0.5 X1 X1^T x - X1 X2^T w - 0.5 Y1 x + 0.5 Y1^T x - U w - 0.5 eps x
  dim3 tg(4, TCH);
  t_partial_kernel<<<tg, 256, 0, stream>>>(X, x, w, tpart);
  t_reduce_kernel<<<NT / 256, 256, 0, stream>>>(tpart, t);
  r_kernel<<<NQ2, 256, 0, stream>>>(X, Y1, U, t, x, w, r);
  tgemv_part_kernel<<<gdim, 256, 0, stream>>>(Y1, x, gpart);
  finish_kernel<1><<<NQ2 / 256, 256, 0, stream>>>(gpart, invlam, D12, u, r);

  // P = XP XP^T + eps I (lower) into M, Cholesky in place
  syrk_lower_kernel<<<nsyrk, 256, 0, stream>>>(XP, NQ2, NQ2, M, FEPS);
  for (int k = 0; k < NBLK; k++) {
    chol_diag_kernel<<<1, 64, 0, stream>>>(M, k);
    int rows_below = NQ2 - (k + 1) * NB;
    if (rows_below > 0) {
      chol_panel_kernel<<<(rows_below + 255) / 256, 256, 0, stream>>>(M, k);
      int m = NBLK - 1 - k;
      chol_trail_kernel<<<m * (m + 1) / 2, 256, 0, stream>>>(M, k);
    }
  }

  // solve P z = r
  fwd_solve_kernel<1><<<1, 1024, 0, stream>>>(M, r, invlam, y);
  bwd_solve_kernel<<<1, 1024, 0, stream>>>(M, y, z);

  // 2 steps of iterative refinement (residual via matvecs, P never re-formed)
  for (int it = 0; it < 2; it++) {
    tgemv_part_kernel<<<gdim, 256, 0, stream>>>(XP, z, gpart);
    finish_kernel<2><<<NQ2 / 256, 256, 0, stream>>>(gpart, invlam, D12, u, t);
    pz2_res_kernel<<<NQ2, 256, 0, stream>>>(XP, t, z, r, res);
    fwd_solve_kernel<1><<<1, 1024, 0, stream>>>(M, res, invlam, y);
    bwd_solve_kernel<<<1, 1024, 0, stream>>>(M, y, dz);
    axpy_kernel<<<NQ2 / 256, 256, 0, stream>>>(z, dz);
  }

  out_kernel<<<NQ2 / 256, 256, 0, stream>>>(z, B2, u, out);
}

// Round 3
// 5661.383 us; speedup vs baseline: 1.6722x; 1.5892x over previous
//
#include <hip/hip_runtime.h>
#include <math.h>

#define NQ2 2048      // nx = nq = 2048
#define NT  4096      // nx + nq
#define NUU 16
#define FEPS 0.01f
#define NB  64
#define NBLK 32       // 2048 / 64
#define ST  128       // syrk tile
#define SBK 16
#define GCH 16        // split-K chunks for transposed GEMVs

__device__ __forceinline__ float readlane_f(float v, int lane) {
  return __int_as_float(__builtin_amdgcn_readlane(__float_as_int(v), lane));
}

// ---------------- reductions ----------------
__device__ __forceinline__ float wave_reduce(float v) {
#pragma unroll
  for (int off = 32; off > 0; off >>= 1) v += __shfl_down(v, off, 64);
  return v;
}

__device__ __forceinline__ float block_reduce_256(float v) {
  __shared__ float sm[4];
  v = wave_reduce(v);
  if ((threadIdx.x & 63) == 0) sm[threadIdx.x >> 6] = v;
  __syncthreads();
  return (threadIdx.x == 0) ? (sm[0] + sm[1] + sm[2] + sm[3]) : 0.0f;
}

// ---------------- lam: inv(0.5*(||X2 row||^2 + eps)) ----------------
__global__ __launch_bounds__(256) void lam_kernel(const float* __restrict__ X,
                                                  float* __restrict__ invlam) {
  int row = blockIdx.x;
  const float* xr = X + (size_t)(NQ2 + row) * NT;
  float s = 0.f;
  for (int k = threadIdx.x * 4; k < NT; k += 1024) {
    float4 v = *(const float4*)(xr + k);
    s += v.x * v.x + v.y * v.y + v.z * v.z + v.w * v.w;
  }
  float tot = block_reduce_256(s);
  if (threadIdx.x == 0) invlam[row] = 1.0f / (0.5f * (tot + FEPS));
}

// ---------------- split-K transposed GEMV: part[ch][col] = sum_i A[i][col] v[i] ----
__global__ __launch_bounds__(256) void tgemv_part_kernel(const float* __restrict__ A,
                                                         const float* __restrict__ v,
                                                         float* __restrict__ part) {
  int col = blockIdx.x * 256 + threadIdx.x;
  int ch = blockIdx.y;
  int i0 = ch * (NQ2 / GCH), i1 = i0 + NQ2 / GCH;
  float s = 0.f;
#pragma unroll 4
  for (int i = i0; i < i1; i++) s = fmaf(A[(size_t)i * NQ2 + col], v[i], s);
  part[(size_t)ch * NQ2 + col] = s;
}

// FM 0: c = sum*invlam + D12 u   FM 1: r += 0.5*sum   FM 2: dst = sum
template <int FM>
__global__ __launch_bounds__(256) void finish_kernel(const float* __restrict__ part,
                                                     const float* __restrict__ invlam,
                                                     const float* __restrict__ D12,
                                                     const float* __restrict__ u,
                                                     float* __restrict__ dst) {
  int col = blockIdx.x * 256 + threadIdx.x;
  float s = 0.f;
#pragma unroll
  for (int ch = 0; ch < GCH; ch++) s += part[(size_t)ch * NQ2 + col];
  if (FM == 0) {
    float d = 0.f;
#pragma unroll
    for (int j = 0; j < NUU; j++) d += D12[(size_t)col * NUU + j] * u[j];
    dst[col] = s * invlam[col] + d;
  } else if (FM == 1) {
    dst[col] += 0.5f * s;
  } else {
    dst[col] = s;
  }
}

// ---------------- SYRK (lower 128-tiles): C = A A^T (+ eps on diag) ----------------
__global__ __launch_bounds__(256) void syrk_lower_kernel(const float* __restrict__ A,
                                                         int lda, int K,
                                                         float* __restrict__ C, float eps) {
  int L = blockIdx.x;
  int bi = (int)((sqrtf(8.0f * (float)L + 1.0f) - 1.0f) * 0.5f);
  while ((bi + 1) * (bi + 2) / 2 <= L) bi++;
  while (bi * (bi + 1) / 2 > L) bi--;
  int bj = L - bi * (bi + 1) / 2;
  int row0 = bi * ST, col0 = bj * ST;

  __shared__ float As[SBK][ST];
  __shared__ float Bs[SBK][ST];
  int tid = threadIdx.x;
  int tx = tid & 15, ty = tid >> 4;
  int sr = tid >> 1;            // staging row 0..127
  int ks = (tid & 1) * 8;       // staging k offset 0 or 8

  float4 a0, a1, b0, b1;
  {
    const float* ap = A + (size_t)(row0 + sr) * lda + ks;
    const float* bp = A + (size_t)(col0 + sr) * lda + ks;
    a0 = *(const float4*)(ap); a1 = *(const float4*)(ap + 4);
    b0 = *(const float4*)(bp); b1 = *(const float4*)(bp + 4);
  }

  float acc[8][8] = {{0.f}};
  for (int k0 = 0; k0 < K; k0 += SBK) {
    __syncthreads();
    As[ks + 0][sr] = a0.x; As[ks + 1][sr] = a0.y; As[ks + 2][sr] = a0.z; As[ks + 3][sr] = a0.w;
    As[ks + 4][sr] = a1.x; As[ks + 5][sr] = a1.y; As[ks + 6][sr] = a1.z; As[ks + 7][sr] = a1.w;
    Bs[ks + 0][sr] = b0.x; Bs[ks + 1][sr] = b0.y; Bs[ks + 2][sr] = b0.z; Bs[ks + 3][sr] = b0.w;
    Bs[ks + 4][sr] = b1.x; Bs[ks + 5][sr] = b1.y; Bs[ks + 6][sr] = b1.z; Bs[ks + 7][sr] = b1.w;
    __syncthreads();
    if (k0 + SBK < K) {
      const float* ap = A + (size_t)(row0 + sr) * lda + k0 + SBK + ks;
      const float* bp = A + (size_t)(col0 + sr) * lda + k0 + SBK + ks;
      a0 = *(const float4*)(ap); a1 = *(const float4*)(ap + 4);
      b0 = *(const float4*)(bp); b1 = *(const float4*)(bp + 4);
    }
#pragma unroll
    for (int k = 0; k < SBK; k++) {
      float4 aL = *(const float4*)&As[k][ty * 4];
      float4 aH = *(const float4*)&As[k][64 + ty * 4];
      float4 bL = *(const float4*)&Bs[k][tx * 4];
      float4 bH = *(const float4*)&Bs[k][64 + tx * 4];
      float aa[8] = {aL.x, aL.y, aL.z, aL.w, aH.x, aH.y, aH.z, aH.w};
      float bb[8] = {bL.x, bL.y, bL.z, bL.w, bH.x, bH.y, bH.z, bH.w};
#pragma unroll
      for (int i = 0; i < 8; i++)
#pragma unroll
        for (int j = 0; j < 8; j++) acc[i][j] = fmaf(aa[i], bb[j], acc[i][j]);
    }
  }

  bool diag = (row0 == col0);
#pragma unroll
  for (int ii = 0; ii < 8; ii++) {
    int gi = row0 + ((ii >> 2) * 64) + ty * 4 + (ii & 3);
#pragma unroll
    for (int half = 0; half < 2; half++) {
      int gj0 = col0 + half * 64 + tx * 4;
      float4 o;
      o.x = acc[ii][half * 4 + 0]; o.y = acc[ii][half * 4 + 1];
      o.z = acc[ii][half * 4 + 2]; o.w = acc[ii][half * 4 + 3];
      if (diag) {
        if (gi == gj0 + 0) o.x += eps;
        if (gi == gj0 + 1) o.y += eps;
        if (gi == gj0 + 2) o.z += eps;
        if (gi == gj0 + 3) o.w += eps;
      }
      *(float4*)&C[(size_t)gi * NQ2 + gj0] = o;
    }
  }
}

// ---------------- blocked forward substitution (readlane serial chain) ----------------
// MODE 0: w_i = relu(c_i - (sum_{j<i} M[i,j] w_j) * invlam_i)    (M = H22, strict lower)
// MODE 1: y_i = (r_i - sum_{j<i} L[i,j] y_j) / L[i,i]            (M = L)
template <int MODE>
__global__ __launch_bounds__(1024) void fwd_solve_kernel(const float* __restrict__ M_,
                                                         const float* __restrict__ rhs,
                                                         const float* __restrict__ invlam,
                                                         float* __restrict__ out) {
  __shared__ float partial[NQ2];
  __shared__ float il[NQ2];
  __shared__ float tile[NB][NB + 1];
  __shared__ float vblk[NB];
  int tid = threadIdx.x;
  int rquad = tid >> 2;   // 0..255
  int l4 = tid & 3;       // 0..3
  for (int i = tid; i < NQ2; i += 1024) {
    partial[i] = rhs[i];
    if (MODE == 0) il[i] = invlam[i];
  }
  __syncthreads();
  for (int b = 0; b < NBLK; b++) {
    int b0 = b * NB;
    for (int e = tid; e < NB * NB; e += 1024) {
      int rr = e >> 6, cc = e & 63;
      tile[rr][cc] = M_[(size_t)(b0 + rr) * NQ2 + b0 + cc];
    }
    __syncthreads();
    if (tid < 64) {
      int l = tid;
      float creg = partial[b0 + l];
      float ilreg = (MODE == 0) ? il[b0 + l] : 0.f;
      float dinv = (MODE == 1) ? (1.0f / tile[l][l]) : 0.f;
      float acc = 0.f;
      float wfin = 0.f;
#pragma unroll
      for (int i = 0; i < NB; i++) {
        float cand;
        if (MODE == 0) cand = fmaxf(creg - acc * ilreg, 0.f);
        else           cand = (creg - acc) * dinv;
        float wi = readlane_f(cand, i);
        acc = fmaf(tile[l][i], wi, acc);
        if (l == i) wfin = wi;
      }
      vblk[l] = wfin;
      out[b0 + l] = wfin;
    }
    __syncthreads();
    // GEMV update: 4 lanes per row, 4 independent float4 loads per lane
    for (int base = b0 + NB; base < NQ2; base += 256) {
      int row = base + rquad;
      float acc = 0.f;
      if (row < NQ2) {
        const float* mr = M_ + (size_t)row * NQ2 + b0 + l4 * 16;
        float4 m0 = *(const float4*)(mr);
        float4 m1 = *(const float4*)(mr + 4);
        float4 m2 = *(const float4*)(mr + 8);
        float4 m3 = *(const float4*)(mr + 12);
        const float* vp = &vblk[l4 * 16];
        float4 v0 = *(const float4*)(vp);
        float4 v1 = *(const float4*)(vp + 4);
        float4 v2 = *(const float4*)(vp + 8);
        float4 v3 = *(const float4*)(vp + 12);
        acc = m0.x * v0.x + m0.y * v0.y + m0.z * v0.z + m0.w * v0.w
            + m1.x * v1.x + m1.y * v1.y + m1.z * v1.z + m1.w * v1.w
            + m2.x * v2.x + m2.y * v2.y + m2.z * v2.z + m2.w * v2.w
            + m3.x * v3.x + m3.y * v3.y + m3.z * v3.z + m3.w * v3.w;
      }
      acc += __shfl_xor(acc, 1);
      acc += __shfl_xor(acc, 2);
      if (l4 == 0 && row < NQ2) {
        if (MODE == 0) partial[row] -= acc * il[row];
        else           partial[row] -= acc;
      }
    }
    __syncthreads();
  }
}

// ---------------- blocked backward substitution: L^T z = y ----------------
__global__ __launch_bounds__(1024) void bwd_solve_kernel(const float* __restrict__ M_,
                                                         const float* __restrict__ rhs,
                                                         float* __restrict__ out) {
  __shared__ float partial[NQ2];
  __shared__ float tile[NB][NB + 1];  // tile[a][b] = L[b0+b][b0+a]
  __shared__ float vblk[NB];
  int tid = threadIdx.x;
  for (int i = tid; i < NQ2; i += 1024) partial[i] = rhs[i];
  __syncthreads();
  for (int b = NBLK - 1; b >= 0; b--) {
    int b0 = b * NB;
    for (int e = tid; e < NB * NB; e += 1024) {
      int rr = e >> 6, cc = e & 63;
      tile[cc][rr] = M_[(size_t)(b0 + rr) * NQ2 + b0 + cc];
    }
    __syncthreads();
    if (tid < 64) {
      int l = tid;
      float creg = partial[b0 + l];
      float dinv = 1.0f / tile[l][l];
      float acc = 0.f;
      float zfin = 0.f;
#pragma unroll
      for (int i = NB - 1; i >= 0; i--) {
        float cand = (creg - acc) * dinv;
        float zi = readlane_f(cand, i);
        acc = fmaf(tile[l][i], zi, acc);   // tile[l][i] = L[b0+i][b0+l]
        if (l == i) zfin = zi;
      }
      vblk[l] = zfin;
      out[b0 + l] = zfin;
    }
    __syncthreads();
    for (int i = tid; i < b0; i += 1024) {
      float acc = 0.f;
#pragma unroll 8
      for (int l = 0; l < NB; l++) acc += M_[(size_t)(b0 + l) * NQ2 + i] * vblk[l];
      partial[i] -= acc;
    }
    __syncthreads();
  }
}

// ---------------- Cholesky: diag factor ----------------
__global__ __launch_bounds__(64) void chol_diag_kernel(float* __restrict__ M_, int k) {
  __shared__ float A[NB][NB + 1];
  int tid = threadIdx.x;
  int b0 = k * NB;
  for (int cn = 0; cn < NB; cn++) A[tid][cn] = M_[(size_t)(b0 + tid) * NQ2 + b0 + cn];
  __syncthreads();
  for (int j = 0; j < NB; j++) {
    if (tid == j) A[j][j] = sqrtf(fmaxf(A[j][j], 1e-12f));
    __syncthreads();
    if (tid > j) A[tid][j] /= A[j][j];
    __syncthreads();
    if (tid > j) {
      float lij = A[tid][j];
      for (int jj = j + 1; jj <= tid; jj++) A[tid][jj] -= lij * A[jj][j];
    }
    __syncthreads();
  }
  for (int cn = 0; cn <= tid; cn++) M_[(size_t)(b0 + tid) * NQ2 + b0 + cn] = A[tid][cn];
}

// ---------------- Cholesky: panel solve L21 = A21 L11^{-T} ----------------
__global__ __launch_bounds__(256) void chol_panel_kernel(float* __restrict__ M_, int k) {
  __shared__ float L11[NB][NB + 1];
  int b0 = k * NB;
  for (int e = threadIdx.x; e < NB * NB; e += 256) {
    int rr = e >> 6, cc = e & 63;
    L11[rr][cc] = M_[(size_t)(b0 + rr) * NQ2 + b0 + cc];
  }
  __syncthreads();
  int row = b0 + NB + blockIdx.x * 256 + threadIdx.x;
  if (row >= NQ2) return;
  float v[NB];
  const float* ar = M_ + (size_t)row * NQ2 + b0;
#pragma unroll
  for (int j = 0; j < NB; j += 4) {
    float4 a = *(const float4*)(ar + j);
    v[j] = a.x; v[j + 1] = a.y; v[j + 2] = a.z; v[j + 3] = a.w;
  }
#pragma unroll
  for (int j = 0; j < NB; j++) {
    float s = v[j];
#pragma unroll
    for (int tt = 0; tt < j; tt++) s -= v[tt] * L11[j][tt];
    v[j] = s / L11[j][j];
  }
  float* wr = M_ + (size_t)row * NQ2 + b0;
#pragma unroll
  for (int j = 0; j < NB; j += 4) {
    float4 a; a.x = v[j]; a.y = v[j + 1]; a.z = v[j + 2]; a.w = v[j + 3];
    *(float4*)(wr + j) = a;
  }
}

// ---------------- Cholesky: trailing update A22 -= L21 L21^T (lower tiles) --------
__global__ __launch_bounds__(256) void chol_trail_kernel(float* __restrict__ M_, int k) {
  int L = blockIdx.x;
  int bi_ = (int)((sqrtf(8.0f * (float)L + 1.0f) - 1.0f) * 0.5f);
  while ((bi_ + 1) * (bi_ + 2) / 2 <= L) bi_++;
  while (bi_ * (bi_ + 1) / 2 > L) bi_--;
  int bj_ = L - bi_ * (bi_ + 1) / 2;
  int bi = k + 1 + bi_, bj = k + 1 + bj_;
  int row0 = bi * NB, col0 = bj * NB, kc = k * NB;
  __shared__ float As[NB][NB + 1];
  __shared__ float Bs[NB][NB + 1];
  int tid = threadIdx.x;
  for (int e = tid; e < NB * NB; e += 256) {
    int rr = e >> 6, cc = e & 63;
    As[rr][cc] = M_[(size_t)(row0 + rr) * NQ2 + kc + cc];
    Bs[rr][cc] = M_[(size_t)(col0 + rr) * NQ2 + kc + cc];
  }
  __syncthreads();
  int tx = tid & 15, ty = tid >> 4;
  float acc[4][4] = {{0.f}};
#pragma unroll 8
  for (int t = 0; t < NB; t++) {
    float aa[4], bb[4];
#pragma unroll
    for (int i = 0; i < 4; i++) aa[i] = As[ty * 4 + i][t];
#pragma unroll
    for (int j = 0; j < 4; j++) bb[j] = Bs[tx * 4 + j][t];
#pragma unroll
    for (int i = 0; i < 4; i++)
#pragma unroll
      for (int j = 0; j < 4; j++) acc[i][j] = fmaf(aa[i], bb[j], acc[i][j]);
  }
#pragma unroll
  for (int i = 0; i < 4; i++) {
    float* cp = &M_[(size_t)(row0 + ty * 4 + i) * NQ2 + col0 + tx * 4];
    float4 v = *(const float4*)cp;
    v.x -= acc[i][0]; v.y -= acc[i][1]; v.z -= acc[i][2]; v.w -= acc[i][3];
    *(float4*)cp = v;
  }
}

// ---------------- t = -0.5 X1^T x - X2^T w (split over row chunks) ----------------
#define TCH 32
__global__ __launch_bounds__(256) void t_partial_kernel(const float* __restrict__ X,
                                                        const float* __restrict__ x,
                                                        const float* __restrict__ w,
                                                        float* __restrict__ tpart) {
  int k4 = (blockIdx.x * 256 + threadIdx.x) * 4;
  int chunk = blockIdx.y;
  int i0 = chunk * (NT / TCH);
  float4 acc = {0.f, 0.f, 0.f, 0.f};
  for (int i = i0; i < i0 + NT / TCH; i++) {
    float cf = (i < NQ2) ? (-0.5f * x[i]) : (-w[i - NQ2]);
    float4 xv = *(const float4*)(X + (size_t)i * NT + k4);
    acc.x += cf * xv.x; acc.y += cf * xv.y; acc.z += cf * xv.z; acc.w += cf * xv.w;
  }
  *(float4*)(tpart + (size_t)chunk * NT + k4) = acc;
}

__global__ __launch_bounds__(256) void t_reduce_kernel(const float* __restrict__ tpart,
                                                       float* __restrict__ t) {
  int k = blockIdx.x * 256 + threadIdx.x;
  float s = 0.f;
#pragma unroll 8
  for (int ch = 0; ch < TCH; ch++) s += tpart[(size_t)ch * NT + k];
  t[k] = s;
}

// -------- r = X1 t - 0.5 Y1 x - U w - 0.5 eps x  (per-row dot reductions) --------
__global__ __launch_bounds__(256) void r_kernel(const float* __restrict__ X,
                                                const float* __restrict__ Y1,
                                                const float* __restrict__ U,
                                                const float* __restrict__ t,
                                                const float* __restrict__ x,
                                                const float* __restrict__ w,
                                                float* __restrict__ r) {
  int row = blockIdx.x;
  float s1 = 0.f, s2 = 0.f, s3 = 0.f;
  const float* xr = X + (size_t)row * NT;
  for (int k = threadIdx.x * 4; k < NT; k += 1024) {
    float4 a = *(const float4*)(xr + k);
    float4 b = *(const float4*)(t + k);
    s1 += a.x * b.x + a.y * b.y + a.z * b.z + a.w * b.w;
  }
  const float* yr = Y1 + (size_t)row * NQ2;
  const float* ur = U + (size_t)row * NQ2;
  for (int k = threadIdx.x * 4; k < NQ2; k += 1024) {
    float4 a = *(const float4*)(yr + k);
    float4 b = *(const float4*)(x + k);
    s2 += a.x * b.x + a.y * b.y + a.z * b.z + a.w * b.w;
    float4 c2 = *(const float4*)(ur + k);
    float4 d2 = *(const float4*)(w + k);
    s3 += c2.x * d2.x + c2.y * d2.y + c2.z * d2.z + c2.w * d2.w;
  }
  float v = s1 - 0.5f * s2 - s3;
  float tot = block_reduce_256(v);
  if (threadIdx.x == 0) r[row] = tot - 0.5f * FEPS * x[row];
}

// ---------------- IR: res = r - (XP pz1 + eps z) ----------------
__global__ __launch_bounds__(256) void pz2_res_kernel(const float* __restrict__ XP,
                                                      const float* __restrict__ pz1,
                                                      const float* __restrict__ z,
                                                      const float* __restrict__ r,
                                                      float* __restrict__ res) {
  int row = blockIdx.x;
  float s = 0.f;
  const float* xr = XP + (size_t)row * NQ2;
  for (int k = threadIdx.x * 4; k < NQ2; k += 1024) {
    float4 a = *(const float4*)(xr + k);
    float4 b = *(const float4*)(pz1 + k);
    s += a.x * b.x + a.y * b.y + a.z * b.z + a.w * b.w;
  }
  float tot = block_reduce_256(s);
  if (threadIdx.x == 0) res[row] = r[row] - (tot + FEPS * z[row]);
}

__global__ __launch_bounds__(256) void axpy_kernel(float* __restrict__ z,
                                                   const float* __restrict__ dz) {
  int i = blockIdx.x * 256 + threadIdx.x;
  z[i] += dz[i];
}

// ---------------- out = z + B2 u ----------------
__global__ __launch_bounds__(256) void out_kernel(const float* __restrict__ z,
                                                  const float* __restrict__ B2,
                                                  const float* __restrict__ u,
                                                  float* __restrict__ out) {
  int i = blockIdx.x * 256 + threadIdx.x;
  float s = 0.f;
#pragma unroll
  for (int j = 0; j < NUU; j++) s += B2[(size_t)i * NUU + j] * u[j];
  out[i] = z[i] + s;
}

extern "C" void kernel_launch(void* const* d_in, const int* in_sizes, int n_in,
                              void* d_out, int out_size, void* d_ws, size_t ws_size,
                              hipStream_t stream) {
  (void)in_sizes; (void)n_in; (void)out_size; (void)ws_size;
  const float* x   = (const float*)d_in[1];
  const float* u   = (const float*)d_in[2];
  const float* X   = (const float*)d_in[3];
  const float* U   = (const float*)d_in[4];
  const float* Y1  = (const float*)d_in[5];
  const float* XP  = (const float*)d_in[6];
  const float* B2  = (const float*)d_in[7];
  const float* D12 = (const float*)d_in[8];
  float* out = (float*)d_out;

  float* ws     = (float*)d_ws;
  float* M      = ws;                           // 2048*2048, holds H22 then P/L
  float* vecs   = ws + (size_t)NQ2 * NQ2;
  float* invlam = vecs;
  float* c      = vecs + 2048;
  float* w      = vecs + 4096;
  float* r      = vecs + 6144;
  float* y      = vecs + 8192;
  float* z      = vecs + 10240;
  float* dz     = vecs + 12288;
  float* res    = vecs + 14336;
  float* t      = vecs + 16384;                 // 4096 (also reused as pz1)
  float* tpart  = vecs + 20480;                 // 32*4096 (also reused as gpart 16*2048)
  float* gpart  = tpart;

  int nsyrk = (NQ2 / ST) * (NQ2 / ST + 1) / 2;  // 136
  dim3 gdim(NQ2 / 256, GCH);

  // lam, c = (U^T x)/lam + D12 u
  lam_kernel<<<NQ2, 256, 0, stream>>>(X, invlam);
  tgemv_part_kernel<<<gdim, 256, 0, stream>>>(U, x, gpart);
  finish_kernel<0><<<NQ2 / 256, 256, 0, stream>>>(gpart, invlam, D12, u, c);

  // H22 (strict lower used) into M, then sequential relu-triangular solve for w
  syrk_lower_kernel<<<nsyrk, 256, 0, stream>>>(X + (size_t)NQ2 * NT, NT, NT, M, 0.0f);
  fwd_solve_kernel<0><<<1, 1024, 0, stream>>>(M, c, invlam, w);

  // r = -0.5 X1 X1^T x - X1 X2^T w - 0.5 Y1 x + 0.5 Y1^T x - U w - 0.5 eps x
  dim3 tg(4, TCH);
  t_partial_kernel<<<tg, 256, 0, stream>>>(X, x, w, tpart);
  t_reduce_kernel<<<NT / 256, 256, 0, stream>>>(tpart, t);
  r_kernel<<<NQ2, 256, 0, stream>>>(X, Y1, U, t, x, w, r);
  tgemv_part_kernel<<<gdim, 256, 0, stream>>>(Y1, x, gpart);
  finish_kernel<1><<<NQ2 / 256, 256, 0, stream>>>(gpart, invlam, D12, u, r);

  // P = XP XP^T + eps I (lower) into M, Cholesky in place
  syrk_lower_kernel<<<nsyrk, 256, 0, stream>>>(XP, NQ2, NQ2, M, FEPS);
  for (int k = 0; k < NBLK; k++) {
    chol_diag_kernel<<<1, 64, 0, stream>>>(M, k);
    int rows_below = NQ2 - (k + 1) * NB;
    if (rows_below > 0) {
      chol_panel_kernel<<<(rows_below + 255) / 256, 256, 0, stream>>>(M, k);
      int m = NBLK - 1 - k;
      chol_trail_kernel<<<m * (m + 1) / 2, 256, 0, stream>>>(M, k);
    }
  }

  // solve P z = r
  fwd_solve_kernel<1><<<1, 1024, 0, stream>>>(M, r, invlam, y);
  bwd_solve_kernel<<<1, 1024, 0, stream>>>(M, y, z);

  // 2 steps of iterative refinement (residual via matvecs, P never re-formed)
  for (int it = 0; it < 2; it++) {
    tgemv_part_kernel<<<gdim, 256, 0, stream>>>(XP, z, gpart);
    finish_kernel<2><<<NQ2 / 256, 256, 0, stream>>>(gpart, invlam, D12, u, t);
    pz2_res_kernel<<<NQ2, 256, 0, stream>>>(XP, t, z, r, res);
    fwd_solve_kernel<1><<<1, 1024, 0, stream>>>(M, res, invlam, y);
    bwd_solve_kernel<<<1, 1024, 0, stream>>>(M, y, dz);
    axpy_kernel<<<NQ2 / 256, 256, 0, stream>>>(z, dz);
  }

  out_kernel<<<NQ2 / 256, 256, 0, stream>>>(z, B2, u, out);
}